// Round 2
// baseline (449.219 us; speedup 1.0000x reference)
//
#include <hip/hip_runtime.h>

#define NUM_CLASSES 19
#define IGNORE_INDEX (-1)
#define BATCH 8
#define HW (512 * 1024)            // pixels per image, 2^19
#define NPIX (BATCH * HW)          // 4,194,304
#define NGROUP (NPIX / 4)          // 1,048,576 float4 groups
#define NBINS (3 * NUM_CLASSES)    // 57: label | pred | intersect
#define BINS_PAD 64                // padded per-block output slot
#define HBLOCKS 2048               // hist grid size

// Histogram kernel: one thread handles 4 consecutive pixels (float4/int4 loads).
// Per-wave LDS sub-histograms -> block reduce -> PLAIN stores of per-block
// partials into d_ws (no global atomics, no pre-zeroing of d_ws needed).
__global__ __launch_bounds__(256) void iou_hist_kernel(
    const float* __restrict__ pred,
    const int* __restrict__ label,
    unsigned int* __restrict__ bh)
{
    __shared__ unsigned int h[4][NBINS];  // one sub-histogram per wave
    const int tid = threadIdx.x;
    const int wid = tid >> 6;             // wave id within block (wave64)

    for (int i = tid; i < 4 * NBINS; i += 256) ((unsigned int*)h)[i] = 0u;
    __syncthreads();

    unsigned int* __restrict__ hw_ = h[wid];

    const int stride = HBLOCKS * 256;
    for (int g = blockIdx.x * 256 + tid; g < NGROUP; g += stride) {
        const int p  = g << 2;                 // first pixel of group
        const int b  = p >> 19;                // p / HW
        const int hw = p & (HW - 1);           // p % HW

        const float* bp = pred + (long)b * (long)(NUM_CLASSES * (long)HW) + hw;
        float4 best = *(const float4*)bp;
        int bcx = 0, bcy = 0, bcz = 0, bcw = 0;
#pragma unroll
        for (int c = 1; c < NUM_CLASSES; ++c) {
            bp += HW;
            const float4 v = *(const float4*)bp;
            if (v.x > best.x) { best.x = v.x; bcx = c; }
            if (v.y > best.y) { best.y = v.y; bcy = c; }
            if (v.z > best.z) { best.z = v.z; bcz = c; }
            if (v.w > best.w) { best.w = v.w; bcw = c; }
        }

        const int4 lab = ((const int4*)label)[g];

        {
            const int l = lab.x;
            if (l != IGNORE_INDEX) {
                const int lc = min(max(l, 0), NUM_CLASSES - 1);
                atomicAdd(&hw_[lc], 1u);
                atomicAdd(&hw_[NUM_CLASSES + bcx], 1u);
                if (bcx == l) atomicAdd(&hw_[2 * NUM_CLASSES + lc], 1u);
            }
        }
        {
            const int l = lab.y;
            if (l != IGNORE_INDEX) {
                const int lc = min(max(l, 0), NUM_CLASSES - 1);
                atomicAdd(&hw_[lc], 1u);
                atomicAdd(&hw_[NUM_CLASSES + bcy], 1u);
                if (bcy == l) atomicAdd(&hw_[2 * NUM_CLASSES + lc], 1u);
            }
        }
        {
            const int l = lab.z;
            if (l != IGNORE_INDEX) {
                const int lc = min(max(l, 0), NUM_CLASSES - 1);
                atomicAdd(&hw_[lc], 1u);
                atomicAdd(&hw_[NUM_CLASSES + bcz], 1u);
                if (bcz == l) atomicAdd(&hw_[2 * NUM_CLASSES + lc], 1u);
            }
        }
        {
            const int l = lab.w;
            if (l != IGNORE_INDEX) {
                const int lc = min(max(l, 0), NUM_CLASSES - 1);
                atomicAdd(&hw_[lc], 1u);
                atomicAdd(&hw_[NUM_CLASSES + bcw], 1u);
                if (bcw == l) atomicAdd(&hw_[2 * NUM_CLASSES + lc], 1u);
            }
        }
    }

    __syncthreads();
    // per-block partials: every slot written unconditionally (d_ws is poisoned)
    unsigned int* __restrict__ outp = bh + (size_t)blockIdx.x * BINS_PAD;
    for (int i = tid; i < BINS_PAD; i += 256) {
        const unsigned int s = (i < NBINS)
            ? (h[0][i] + h[1][i] + h[2][i] + h[3][i]) : 0u;
        outp[i] = s;
    }
}

// Single-block reduce of HBLOCKS x BINS_PAD partials + final scalar.
// 1 - nanmean(inter/union); union==0 -> NaN -> skipped; all-NaN -> 0.5.
__global__ __launch_bounds__(1024) void iou_finish_kernel(
    const unsigned int* __restrict__ bh, float* __restrict__ out)
{
    __shared__ unsigned int part[16][BINS_PAD];
    const int tid = threadIdx.x;
    const int bin = tid & 63;
    const int row = tid >> 6;   // 0..15

    unsigned int s = 0;
    for (int b = row; b < HBLOCKS; b += 16)
        s += bh[(size_t)b * BINS_PAD + bin];   // coalesced across tid
    part[row][bin] = s;
    __syncthreads();

    if (tid < BINS_PAD) {
        unsigned int t = 0;
#pragma unroll
        for (int r = 0; r < 16; ++r) t += part[r][tid];
        part[0][tid] = t;
    }
    __syncthreads();

    if (tid == 0) {
        float sum = 0.0f;
        int cnt = 0;
        for (int c = 0; c < NUM_CLASSES; ++c) {
            const float a_lab = (float)part[0][c];
            const float a_prd = (float)part[0][NUM_CLASSES + c];
            const float a_int = (float)part[0][2 * NUM_CLASSES + c];
            const float a_uni = a_prd + a_lab - a_int;
            if (a_uni > 0.0f) { sum += a_int / a_uni; ++cnt; }
        }
        const float mean = (cnt > 0) ? (sum / (float)cnt) : 0.5f;
        out[0] = 1.0f - mean;
    }
}

extern "C" void kernel_launch(void* const* d_in, const int* in_sizes, int n_in,
                              void* d_out, int out_size, void* d_ws, size_t ws_size,
                              hipStream_t stream)
{
    const float* pred  = (const float*)d_in[0];
    const int*   label = (const int*)d_in[1];
    float*       out   = (float*)d_out;
    unsigned int* bh   = (unsigned int*)d_ws;   // HBLOCKS * BINS_PAD uints (512 KB)

    iou_hist_kernel<<<HBLOCKS, 256, 0, stream>>>(pred, label, bh);
    iou_finish_kernel<<<1, 1024, 0, stream>>>(bh, out);
}

// Round 3
// 442.023 us; speedup vs baseline: 1.0163x; 1.0163x over previous
//
#include <hip/hip_runtime.h>

#define NUM_CLASSES 19
#define IGNORE_INDEX (-1)
#define BATCH 8
#define HW (512 * 1024)            // pixels per image, 2^19
#define NPIX (BATCH * HW)          // 4,194,304
#define NGROUP (NPIX / 4)          // 1,048,576 float4 groups
#define NBINS (3 * NUM_CLASSES)    // 57: label | pred | intersect
#define BINS_PAD 64                // padded per-block output slot
#define HBLOCKS 4096               // NGROUP / 256 — one group per thread

// Straight-line histogram kernel: one thread handles exactly 4 consecutive
// pixels (one float4 per class plane, 19 independent constant-offset loads).
// No grid-stride loop, no serial pointer chain -> max memory-level parallelism.
// Per-wave LDS sub-histograms -> block reduce -> plain per-block partial store.
__global__ __launch_bounds__(256) void iou_hist_kernel(
    const float* __restrict__ pred,
    const int* __restrict__ label,
    unsigned int* __restrict__ bh)
{
    __shared__ unsigned int h[4][NBINS];  // one sub-histogram per wave
    const int tid = threadIdx.x;
    const int wid = tid >> 6;             // wave id within block (wave64)

    for (int i = tid; i < 4 * NBINS; i += 256) ((unsigned int*)h)[i] = 0u;
    __syncthreads();

    unsigned int* __restrict__ hw_ = h[wid];

    const int g  = blockIdx.x * 256 + tid;   // 0 .. NGROUP-1
    const int p  = g << 2;                   // first pixel of group
    const int b  = p >> 19;                  // p / HW
    const int hw = p & (HW - 1);             // p % HW

    // base float4 pointer for this pixel group in plane 0 of image b
    const float4* __restrict__ bp4 =
        (const float4*)(pred + (size_t)b * (size_t)(NUM_CLASSES * HW) + hw);

    float4 best = bp4[0];
    int bcx = 0, bcy = 0, bcz = 0, bcw = 0;
#pragma unroll
    for (int c = 1; c < NUM_CLASSES; ++c) {
        const float4 v = bp4[(size_t)c * (HW / 4)];   // independent const offsets
        if (v.x > best.x) { best.x = v.x; bcx = c; }
        if (v.y > best.y) { best.y = v.y; bcy = c; }
        if (v.z > best.z) { best.z = v.z; bcz = c; }
        if (v.w > best.w) { best.w = v.w; bcw = c; }
    }

    const int4 lab = ((const int4*)label)[g];

    {
        const int l = lab.x;
        if (l != IGNORE_INDEX) {
            const int lc = min(max(l, 0), NUM_CLASSES - 1);
            atomicAdd(&hw_[lc], 1u);
            atomicAdd(&hw_[NUM_CLASSES + bcx], 1u);
            if (bcx == l) atomicAdd(&hw_[2 * NUM_CLASSES + lc], 1u);
        }
    }
    {
        const int l = lab.y;
        if (l != IGNORE_INDEX) {
            const int lc = min(max(l, 0), NUM_CLASSES - 1);
            atomicAdd(&hw_[lc], 1u);
            atomicAdd(&hw_[NUM_CLASSES + bcy], 1u);
            if (bcy == l) atomicAdd(&hw_[2 * NUM_CLASSES + lc], 1u);
        }
    }
    {
        const int l = lab.z;
        if (l != IGNORE_INDEX) {
            const int lc = min(max(l, 0), NUM_CLASSES - 1);
            atomicAdd(&hw_[lc], 1u);
            atomicAdd(&hw_[NUM_CLASSES + bcz], 1u);
            if (bcz == l) atomicAdd(&hw_[2 * NUM_CLASSES + lc], 1u);
        }
    }
    {
        const int l = lab.w;
        if (l != IGNORE_INDEX) {
            const int lc = min(max(l, 0), NUM_CLASSES - 1);
            atomicAdd(&hw_[lc], 1u);
            atomicAdd(&hw_[NUM_CLASSES + bcw], 1u);
            if (bcw == l) atomicAdd(&hw_[2 * NUM_CLASSES + lc], 1u);
        }
    }

    __syncthreads();
    // per-block partials: every slot written unconditionally (d_ws is poisoned)
    unsigned int* __restrict__ outp = bh + (size_t)blockIdx.x * BINS_PAD;
    for (int i = tid; i < BINS_PAD; i += 256) {
        const unsigned int s = (i < NBINS)
            ? (h[0][i] + h[1][i] + h[2][i] + h[3][i]) : 0u;
        outp[i] = s;
    }
}

// Single-block reduce of HBLOCKS x BINS_PAD partials + final scalar.
// 1 - nanmean(inter/union); union==0 -> NaN -> skipped; all-NaN -> 0.5.
__global__ __launch_bounds__(1024) void iou_finish_kernel(
    const unsigned int* __restrict__ bh, float* __restrict__ out)
{
    __shared__ unsigned int part[16][BINS_PAD];
    const int tid = threadIdx.x;
    const int bin = tid & 63;
    const int row = tid >> 6;   // 0..15

    unsigned int s = 0;
    for (int b = row; b < HBLOCKS; b += 16)
        s += bh[(size_t)b * BINS_PAD + bin];   // coalesced across tid
    part[row][bin] = s;
    __syncthreads();

    if (tid < BINS_PAD) {
        unsigned int t = 0;
#pragma unroll
        for (int r = 0; r < 16; ++r) t += part[r][tid];
        part[0][tid] = t;
    }
    __syncthreads();

    if (tid == 0) {
        float sum = 0.0f;
        int cnt = 0;
        for (int c = 0; c < NUM_CLASSES; ++c) {
            const float a_lab = (float)part[0][c];
            const float a_prd = (float)part[0][NUM_CLASSES + c];
            const float a_int = (float)part[0][2 * NUM_CLASSES + c];
            const float a_uni = a_prd + a_lab - a_int;
            if (a_uni > 0.0f) { sum += a_int / a_uni; ++cnt; }
        }
        const float mean = (cnt > 0) ? (sum / (float)cnt) : 0.5f;
        out[0] = 1.0f - mean;
    }
}

extern "C" void kernel_launch(void* const* d_in, const int* in_sizes, int n_in,
                              void* d_out, int out_size, void* d_ws, size_t ws_size,
                              hipStream_t stream)
{
    const float* pred  = (const float*)d_in[0];
    const int*   label = (const int*)d_in[1];
    float*       out   = (float*)d_out;
    unsigned int* bh   = (unsigned int*)d_ws;   // HBLOCKS * BINS_PAD uints (1 MB)

    iou_hist_kernel<<<HBLOCKS, 256, 0, stream>>>(pred, label, bh);
    iou_finish_kernel<<<1, 1024, 0, stream>>>(bh, out);
}